// Round 17
// baseline (185.138 us; speedup 1.0000x reference)
//
#include <hip/hip_runtime.h>
#include <hip/hip_cooperative_groups.h>
#include <hip/hip_bf16.h>

namespace cg = cooperative_groups;

#define CC 20480      // columns of X
#define PP 2048       // P
#define NROWS 2047    // rows reduced
#define SRR 10
#define HH 1024
#define NCH 64        // row chunks (32 rows each)

typedef __attribute__((ext_vector_type(8))) short short8;
typedef __attribute__((ext_vector_type(4))) float f32x4;

__device__ __forceinline__ void split_bf16(float v, unsigned short& hi, unsigned short& lo) {
    __hip_bfloat16 h = __float2bfloat16(v);
    float r = v - __bfloat162float(h);
    __hip_bfloat16 l2 = __float2bfloat16(r);
    hi = *(unsigned short*)&h;
    lo = *(unsigned short*)&l2;
}

__device__ __forceinline__ void gload16(const unsigned short* g, unsigned short* lds) {
    __builtin_amdgcn_global_load_lds(
        (const __attribute__((address_space(1))) void*)g,
        (__attribute__((address_space(3))) void*)lds,
        16, 0, 0);
}

#define BM 128
#define BN 64
#define BK 64

// ======================================================================
// Fused cooperative kernel, grid 256 x 512 (1 block/CU, co-resident).
// Phase A: colsum + W2/W3 split.  grid.sync
// Phase B: gemm1 (h2 = relu(relu(x*W1+b1) @ W2^T + b2)), R15 structure.
// Phase C: gemm2 (partial = relu(h2 @ W3^T + b3) . W4), R15 structure.
// Phase D: ysum.
// ======================================================================
__global__ __launch_bounds__(512, 1) void fused_k(
    const float* __restrict__ X, const int* __restrict__ p,
    float* __restrict__ psum,
    const float* __restrict__ W1, const float* __restrict__ b1,
    const float* __restrict__ W2, const float* __restrict__ b2,
    const float* __restrict__ W3, const float* __restrict__ b3,
    const float* __restrict__ W4, const float* __restrict__ b4,
    unsigned short* __restrict__ w2h, unsigned short* __restrict__ w2l,
    unsigned short* __restrict__ w3h, unsigned short* __restrict__ w3l,
    unsigned short* __restrict__ h2h, unsigned short* __restrict__ h2l,
    float* __restrict__ partial, float* __restrict__ out)
{
    __shared__ unsigned short LDSU[3][24576];   // 144 KB, aliased per phase
    cg::grid_group grid = cg::this_grid();
    int b = blockIdx.x, t = threadIdx.x;
    int tid = b * 512 + t;

    // ================= phase A: colsum + W splits =================
    {
        int k = tid & 2047;
        int chunk = tid >> 11;                  // 0..63
        int r0 = chunk * 32;
        int r1 = r0 + 32; if (r1 > NROWS) r1 = NROWS;
        float s = 0.f;
        int base = SRR * k;
        for (int i = r0; i < r1; ++i) {
            int col = base - p[i]; if (col < 0) col += CC;   // p[i] in [0,64)
            s += X[(size_t)i * (size_t)(SRR * CC) + col];
        }
        psum[chunk * PP + k] = s;
        // W2/W3 split: 8 elems each per thread
        int idx = tid * 8;
        #pragma unroll
        for (int q = 0; q < 2; ++q) {
            float4 v2 = *(const float4*)&W2[idx + q * 4];
            float4 v3 = *(const float4*)&W3[idx + q * 4];
            float a2[4] = {v2.x, v2.y, v2.z, v2.w};
            float a3[4] = {v3.x, v3.y, v3.z, v3.w};
            ushort h24[4], l24[4], h34[4], l34[4];
            #pragma unroll
            for (int i = 0; i < 4; ++i) {
                split_bf16(a2[i], h24[i], l24[i]);
                split_bf16(a3[i], h34[i], l34[i]);
            }
            *(ushort4*)&w2h[idx + q * 4] = *(ushort4*)h24;
            *(ushort4*)&w2l[idx + q * 4] = *(ushort4*)l24;
            *(ushort4*)&w3h[idx + q * 4] = *(ushort4*)h34;
            *(ushort4*)&w3l[idx + q * 4] = *(ushort4*)l34;
        }
    }
    grid.sync();

    // ================= phase B: gemm1 =================
    {
        unsigned short* BbF = &LDSU[0][0];              // 3 x 8192 ushorts
        float* w1f = (float*)(BbF + 3 * 8192);
        float* b1f = w1f + 1024;
        float* xv  = b1f + 1024;

        int v = (b & 7) * 32 + (b >> 3);                // XCD-chunked
        int bx = v >> 4, by = v & 15;
        int bm = bx * BM, bn = by * BN;
        int w = t >> 6, l = t & 63;
        int lr = l & 15, lk = l >> 4;
        int wr = w >> 1, wc = w & 1;

        size_t offB = (size_t)(bn + (w >> 1) * 16 + lr) * HH + (w & 1) * 32 + lk * 8;
#define BSTAGE(buf, k0)                                                \
        do {                                                           \
            gload16(w2h + offB + (k0), BbF + (buf) * 8192 + w * 512);  \
            gload16(w2l + offB + (k0), BbF + (buf) * 8192 + 4096 + w * 512); \
        } while (0)

        BSTAGE(0, 0);
        {
            int row = t >> 2, q = t & 3;
            float s = 0.f;
            #pragma unroll
            for (int j = 0; j < 16; ++j) s += psum[(q * 16 + j) * PP + bm + row];
            s += __shfl_xor(s, 1, 64);
            s += __shfl_xor(s, 2, 64);
            if (q == 0) xv[row] = s * (1.0f / (float)NROWS);
            if (t < 256) *(float4*)&w1f[t * 4] = *(const float4*)&W1[t * 4];
            else *(float4*)&b1f[(t - 256) * 4] = *(const float4*)&b1[(t - 256) * 4];
        }
        __syncthreads();

        float x0 = xv[wr * 32 + lr], x1 = xv[wr * 32 + 16 + lr];

        f32x4 acc[2][2];
        #pragma unroll
        for (int i = 0; i < 2; ++i)
            #pragma unroll
            for (int j = 0; j < 2; ++j) acc[i][j] = (f32x4)(0.f);

        int nt = HH / BK;                       // 16
        for (int tt = 0; tt < nt; ++tt) {
            int cur = tt % 3;
            if (tt + 1 < nt) {
                BSTAGE((tt + 1) % 3, (tt + 1) * BK);
                asm volatile("s_waitcnt vmcnt(2)" ::: "memory");
            } else {
                asm volatile("s_waitcnt vmcnt(0)" ::: "memory");
            }
            __builtin_amdgcn_s_barrier();
            __builtin_amdgcn_sched_barrier(0);
            __builtin_amdgcn_s_setprio(1);
            #pragma unroll
            for (int s2 = 0; s2 < 2; ++s2) {
                int k0 = tt * BK + s2 * 32;
                float4 wva = *(const float4*)&w1f[k0 + lk * 8];
                float4 wvb = *(const float4*)&w1f[k0 + lk * 8 + 4];
                float4 bva = *(const float4*)&b1f[k0 + lk * 8];
                float4 bvb = *(const float4*)&b1f[k0 + lk * 8 + 4];
                float wv[8] = {wva.x, wva.y, wva.z, wva.w, wvb.x, wvb.y, wvb.z, wvb.w};
                float bv2[8] = {bva.x, bva.y, bva.z, bva.w, bvb.x, bvb.y, bvb.z, bvb.w};
                ushort ahh[2][8], all2[2][8];
                #pragma unroll
                for (int mi = 0; mi < 2; ++mi) {
                    float xm = mi ? x1 : x0;
                    #pragma unroll
                    for (int j = 0; j < 8; ++j) {
                        float h = fmaf(xm, wv[j], bv2[j]);
                        h = h > 0.f ? h : 0.f;
                        split_bf16(h, ahh[mi][j], all2[mi][j]);
                    }
                }
                short8 bh2[2], bl2[2];
                #pragma unroll
                for (int ni = 0; ni < 2; ++ni) {
                    bh2[ni] = *(const short8*)&BbF[cur * 8192 + ((wc * 2 + ni) * 2 + s2) * 512 + l * 8];
                    bl2[ni] = *(const short8*)&BbF[cur * 8192 + 4096 + ((wc * 2 + ni) * 2 + s2) * 512 + l * 8];
                }
                #pragma unroll
                for (int mi = 0; mi < 2; ++mi) {
                    short8 ah2 = *(short8*)ahh[mi];
                    short8 al2 = *(short8*)all2[mi];
                    #pragma unroll
                    for (int ni = 0; ni < 2; ++ni) {
                        acc[mi][ni] = __builtin_amdgcn_mfma_f32_16x16x32_bf16(ah2, bh2[ni], acc[mi][ni], 0, 0, 0);
                        acc[mi][ni] = __builtin_amdgcn_mfma_f32_16x16x32_bf16(ah2, bl2[ni], acc[mi][ni], 0, 0, 0);
                        acc[mi][ni] = __builtin_amdgcn_mfma_f32_16x16x32_bf16(al2, bh2[ni], acc[mi][ni], 0, 0, 0);
                    }
                }
            }
            __builtin_amdgcn_s_setprio(0);
            __builtin_amdgcn_sched_barrier(0);
        }
#undef BSTAGE

        float bv[2];
        #pragma unroll
        for (int ni = 0; ni < 2; ++ni) bv[ni] = b2[bn + wc * 32 + ni * 16 + lr];
        #pragma unroll
        for (int mi = 0; mi < 2; ++mi)
            #pragma unroll
            for (int ni = 0; ni < 2; ++ni)
                #pragma unroll
                for (int r = 0; r < 4; ++r) {
                    int row = bm + wr * 32 + mi * 16 + lk * 4 + r;
                    int col = bn + wc * 32 + ni * 16 + lr;
                    float vv = acc[mi][ni][r] + bv[ni];
                    vv = vv > 0.f ? vv : 0.f;
                    unsigned short hi, lo;
                    split_bf16(vv, hi, lo);
                    h2h[(size_t)row * HH + col] = hi;
                    h2l[(size_t)row * HH + col] = lo;
                }
    }
    grid.sync();

    // ================= phase C: gemm2 =================
    {
        int v = (b & 7) * 32 + (b >> 3);
        int bx = v >> 4, by = v & 15;
        int bm = bx * BM, bn = by * BN;
        int w = t >> 6, l = t & 63;
        int lr = l & 15, lk = l >> 4;
        int wr = w >> 1, wc = w & 1;

        size_t offA = (size_t)(bm + w * 16 + lr) * HH + lk * 8;
        size_t offB = (size_t)(bn + (w & 3) * 16 + lr) * HH + lk * 8;

#define STAGE(buf, k0)                                                              \
        do {                                                                        \
            unsigned short* L = LDSU[buf];                                          \
            gload16(h2h + offA + (k0),      L + (w * 2 + 0) * 512);                 \
            gload16(h2h + offA + (k0) + 32, L + (w * 2 + 1) * 512);                 \
            gload16(h2l + offA + (k0),      L + 8192 + (w * 2 + 0) * 512);          \
            gload16(h2l + offA + (k0) + 32, L + 8192 + (w * 2 + 1) * 512);          \
            if (w < 4) {                                                            \
                gload16(w3h + offB + (k0),      L + 16384 + ((w & 3) * 2 + 0) * 512);\
                gload16(w3h + offB + (k0) + 32, L + 16384 + ((w & 3) * 2 + 1) * 512);\
            } else {                                                                \
                gload16(w3l + offB + (k0),      L + 20480 + ((w & 3) * 2 + 0) * 512);\
                gload16(w3l + offB + (k0) + 32, L + 20480 + ((w & 3) * 2 + 1) * 512);\
            }                                                                       \
        } while (0)

        f32x4 acc[2][2];
        #pragma unroll
        for (int i = 0; i < 2; ++i)
            #pragma unroll
            for (int j = 0; j < 2; ++j) acc[i][j] = (f32x4)(0.f);

        STAGE(0, 0);

        int nt = HH / BK;                      // 16 steps
        for (int tt = 0; tt < nt; ++tt) {
            int cur = tt % 3;
            if (tt + 1 < nt) {
                STAGE((tt + 1) % 3, (tt + 1) * BK);
                asm volatile("s_waitcnt vmcnt(6)" ::: "memory");
            } else {
                asm volatile("s_waitcnt vmcnt(0)" ::: "memory");
            }
            __builtin_amdgcn_s_barrier();
            __builtin_amdgcn_sched_barrier(0);
            __builtin_amdgcn_s_setprio(1);
            unsigned short* L = LDSU[cur];
            #pragma unroll
            for (int s2 = 0; s2 < 2; ++s2) {
                short8 ah2[2], al2[2], bh2[2], bl2[2];
                #pragma unroll
                for (int mi = 0; mi < 2; ++mi) {
                    ah2[mi] = *(const short8*)&L[((wr * 2 + mi) * 2 + s2) * 512 + l * 8];
                    al2[mi] = *(const short8*)&L[8192 + ((wr * 2 + mi) * 2 + s2) * 512 + l * 8];
                }
                #pragma unroll
                for (int ni = 0; ni < 2; ++ni) {
                    bh2[ni] = *(const short8*)&L[16384 + ((wc * 2 + ni) * 2 + s2) * 512 + l * 8];
                    bl2[ni] = *(const short8*)&L[20480 + ((wc * 2 + ni) * 2 + s2) * 512 + l * 8];
                }
                #pragma unroll
                for (int mi = 0; mi < 2; ++mi)
                    #pragma unroll
                    for (int ni = 0; ni < 2; ++ni) {
                        acc[mi][ni] = __builtin_amdgcn_mfma_f32_16x16x32_bf16(ah2[mi], bh2[ni], acc[mi][ni], 0, 0, 0);
                        acc[mi][ni] = __builtin_amdgcn_mfma_f32_16x16x32_bf16(ah2[mi], bl2[ni], acc[mi][ni], 0, 0, 0);
                        acc[mi][ni] = __builtin_amdgcn_mfma_f32_16x16x32_bf16(al2[mi], bh2[ni], acc[mi][ni], 0, 0, 0);
                    }
            }
            __builtin_amdgcn_s_setprio(0);
            __builtin_amdgcn_sched_barrier(0);
        }
#undef STAGE

        float bv[2], w4v[2];
        #pragma unroll
        for (int ni = 0; ni < 2; ++ni) {
            bv[ni]  = b3[bn + wc * 32 + ni * 16 + lr];
            w4v[ni] = W4[bn + wc * 32 + ni * 16 + lr];
        }
        #pragma unroll
        for (int mi = 0; mi < 2; ++mi) {
            float ps[4];
            #pragma unroll
            for (int r = 0; r < 4; ++r) {
                float acc_d = 0.f;
                #pragma unroll
                for (int ni = 0; ni < 2; ++ni) {
                    float vv = acc[mi][ni][r] + bv[ni];
                    vv = vv > 0.f ? vv : 0.f;
                    acc_d += vv * w4v[ni];
                }
                ps[r] = acc_d;
            }
            #pragma unroll
            for (int r = 0; r < 4; ++r) {
                #pragma unroll
                for (int m2 = 1; m2 < 16; m2 <<= 1) ps[r] += __shfl_xor(ps[r], m2, 64);
            }
            if (lr == 0) {
                #pragma unroll
                for (int r = 0; r < 4; ++r) {
                    int row = bm + wr * 32 + mi * 16 + lk * 4 + r;
                    partial[(size_t)row * 32 + by * 2 + wc] = ps[r];
                }
            }
        }
    }
    grid.sync();

    // ================= phase D: ysum =================
    if (tid < PP) {
        float s = 0.f;
        #pragma unroll
        for (int q = 0; q < 8; ++q) {
            float4 v = *(const float4*)&partial[(size_t)tid * 32 + q * 4];
            s += v.x + v.y + v.z + v.w;
        }
        out[tid] = s + b4[0];
    }
}

extern "C" void kernel_launch(void* const* d_in, const int* in_sizes, int n_in,
                              void* d_out, int out_size, void* d_ws, size_t ws_size,
                              hipStream_t stream) {
    const float* X  = (const float*)d_in[0];
    const int*   p  = (const int*)d_in[1];
    const float* W1 = (const float*)d_in[2];
    const float* b1 = (const float*)d_in[3];
    const float* W2 = (const float*)d_in[4];
    const float* b2 = (const float*)d_in[5];
    const float* W3 = (const float*)d_in[6];
    const float* b3 = (const float*)d_in[7];
    const float* W4 = (const float*)d_in[8];
    const float* b4 = (const float*)d_in[9];
    float* out = (float*)d_out;

    char* ws = (char*)d_ws;
    size_t off = 0;
    float* psum = (float*)(ws + off); off += (size_t)NCH * PP * 4;
    unsigned short* h2h = (unsigned short*)(ws + off); off += (size_t)PP * HH * 2;
    unsigned short* h2l = (unsigned short*)(ws + off); off += (size_t)PP * HH * 2;
    unsigned short* w2h = (unsigned short*)(ws + off); off += (size_t)HH * HH * 2;
    unsigned short* w2l = (unsigned short*)(ws + off); off += (size_t)HH * HH * 2;
    unsigned short* w3h = (unsigned short*)(ws + off); off += (size_t)HH * HH * 2;
    unsigned short* w3l = (unsigned short*)(ws + off); off += (size_t)HH * HH * 2;
    float* partial = (float*)(ws + off); off += (size_t)PP * 32 * 4;

    void* args[] = {
        (void*)&X, (void*)&p, (void*)&psum,
        (void*)&W1, (void*)&b1, (void*)&W2, (void*)&b2,
        (void*)&W3, (void*)&b3, (void*)&W4, (void*)&b4,
        (void*)&w2h, (void*)&w2l, (void*)&w3h, (void*)&w3l,
        (void*)&h2h, (void*)&h2l, (void*)&partial, (void*)&out
    };
    hipLaunchCooperativeKernel((void*)fused_k, dim3(256), dim3(512), args, 0, stream);
}

// Round 18
// 82.144 us; speedup vs baseline: 2.2538x; 2.2538x over previous
//
#include <hip/hip_runtime.h>
#include <hip/hip_bf16.h>

#define CC 20480      // columns of X
#define PP 2048       // P
#define NROWS 2047    // rows reduced
#define SRR 10
#define HH 1024
#define NCH 64        // row chunks (32 rows each)

typedef __attribute__((ext_vector_type(8))) short short8;
typedef __attribute__((ext_vector_type(4))) float f32x4;

// ---------------- split helper ----------------------------------------
__device__ __forceinline__ void split_bf16(float v, unsigned short& hi, unsigned short& lo) {
    __hip_bfloat16 h = __float2bfloat16(v);
    float r = v - __bfloat162float(h);
    __hip_bfloat16 l2 = __float2bfloat16(r);
    hi = *(unsigned short*)&h;
    lo = *(unsigned short*)&l2;
}

// ---------------- pre: colsum (0..511) + W2 split (512..767) + out-init
__global__ __launch_bounds__(256) void pre_k(const float* __restrict__ X,
                                             const int* __restrict__ p,
                                             float* __restrict__ psum,
                                             const float* __restrict__ W2,
                                             unsigned short* __restrict__ w2h,
                                             unsigned short* __restrict__ w2l,
                                             const float* __restrict__ b4,
                                             float* __restrict__ out) {
    int b = blockIdx.x, t = threadIdx.x;
    if (b < 512) {
        int k = (b & 7) * 256 + t;              // 0..2047
        int chunk = b >> 3;                     // 0..63
        int r0 = chunk * 32;
        int r1 = r0 + 32; if (r1 > NROWS) r1 = NROWS;
        float s = 0.f;
        int base = SRR * k;
        for (int i = r0; i < r1; ++i) {
            int col = base - p[i]; if (col < 0) col += CC;   // p[i] in [0,64)
            s += X[(size_t)i * (size_t)(SRR * CC) + col];
        }
        psum[chunk * PP + k] = s;
        return;
    }
    if (b < 768) {
        int bb = b - 512;                        // W2 split
        int idx = bb * 4096 + t * 16;
        #pragma unroll
        for (int q = 0; q < 4; ++q) {
            float4 v = *(const float4*)&W2[idx + q * 4];
            float vv[4] = {v.x, v.y, v.z, v.w};
            ushort hi4[4], lo4[4];
            #pragma unroll
            for (int i = 0; i < 4; ++i) split_bf16(vv[i], hi4[i], lo4[i]);
            *(ushort4*)&w2h[idx + q * 4] = *(ushort4*)hi4;
            *(ushort4*)&w2l[idx + q * 4] = *(ushort4*)lo4;
        }
        return;
    }
    // blocks 768..775: out[k] = b4[0]
    out[(b - 768) * 256 + t] = b4[0];
}

// ---------------- async global->LDS, 16B/lane -------------------------
__device__ __forceinline__ void gload16(const unsigned short* g, unsigned short* lds) {
    __builtin_amdgcn_global_load_lds(
        (const __attribute__((address_space(1))) void*)g,
        (__attribute__((address_space(3))) void*)lds,
        16, 0, 0);
}

#define BM 128
#define BN 64
#define BK 64

// ======================================================================
// GEMM1 (+W3 split riders on blocks 256..511? NO — R16 showed riders
// hurt; W3 split moved back here as pre-GEMM? No: keep R15 exactly -
// W3 split rides gemm1's grid was R16's regression. R15 had it in pre_k.
// RESTORED R15: W3 split in its own 256 pre_k blocks? R15 pre_k was 768
// blocks (colsum + W2); W3 was split by gemm1-rider in R16 (regressed).
// R15 actually split W3 inside gemm1? No - R15 pre_k: colsum + W2 only,
// gemm1 grid 512 with W3 riders... that WAS R16. R15's pre_k had W2+W3
// both (1024 blocks). Restore that here, minus out-init addition.
// ======================================================================
// NOTE: to keep R15 exactly, W3 split stays in pre_k via extra blocks.
__global__ __launch_bounds__(256) void pre3_k(const float* __restrict__ W3,
                                              unsigned short* __restrict__ w3h,
                                              unsigned short* __restrict__ w3l) {
    int bb = blockIdx.x, t = threadIdx.x;
    int idx = bb * 4096 + t * 16;
    #pragma unroll
    for (int q = 0; q < 4; ++q) {
        float4 v = *(const float4*)&W3[idx + q * 4];
        float vv[4] = {v.x, v.y, v.z, v.w};
        ushort hi4[4], lo4[4];
        #pragma unroll
        for (int i = 0; i < 4; ++i) split_bf16(vv[i], hi4[i], lo4[i]);
        *(ushort4*)&w3h[idx + q * 4] = *(ushort4*)hi4;
        *(ushort4*)&w3l[idx + q * 4] = *(ushort4*)lo4;
    }
}

// ======================================================================
// GEMM1: h2 = relu(h1 @ W2^T + b2), h1 = relu(x*W1+b1) on the fly.
// B via global_load_lds, BK=64, triple-buffered, 1 barrier + vmcnt(2)
// per step (R15 structure, 80.2 us best).
// ======================================================================
__global__ __launch_bounds__(512, 2) void gemm1_k(
    const float* __restrict__ psum,
    const float* __restrict__ W1, const float* __restrict__ b1,
    const unsigned short* __restrict__ Bh, const unsigned short* __restrict__ Bl,
    const float* __restrict__ b2,
    unsigned short* __restrict__ Ch, unsigned short* __restrict__ Cl)
{
    __shared__ unsigned short Bb[3][8192];
    __shared__ float w1f[1024], b1f[1024], xv[128];

    int lin = blockIdx.x, t = threadIdx.x;
    int v = (lin & 7) * 32 + (lin >> 3);     // XCD-chunked, grid=256
    int bx = v >> 4, by = v & 15;
    int bm = bx * BM, bn = by * BN;
    int w = t >> 6, l = t & 63;
    int lr = l & 15, lk = l >> 4;
    int wr = w >> 1, wc = w & 1;

    size_t offB = (size_t)(bn + (w >> 1) * 16 + lr) * HH + (w & 1) * 32 + lk * 8;
#define BSTAGE(buf, k0)                                         \
    do {                                                        \
        gload16(Bh + offB + (k0), Bb[buf] + w * 512);           \
        gload16(Bl + offB + (k0), Bb[buf] + 4096 + w * 512);    \
    } while (0)

    BSTAGE(0, 0);
    {
        int row = t >> 2, q = t & 3;
        float s = 0.f;
        #pragma unroll
        for (int j = 0; j < 16; ++j) s += psum[(q * 16 + j) * PP + bm + row];
        s += __shfl_xor(s, 1, 64);
        s += __shfl_xor(s, 2, 64);
        if (q == 0) xv[row] = s * (1.0f / (float)NROWS);
        if (t < 256) *(float4*)&w1f[t * 4] = *(const float4*)&W1[t * 4];
        else *(float4*)&b1f[(t - 256) * 4] = *(const float4*)&b1[(t - 256) * 4];
    }
    __syncthreads();

    float x0 = xv[wr * 32 + lr], x1 = xv[wr * 32 + 16 + lr];

    f32x4 acc[2][2];
    #pragma unroll
    for (int i = 0; i < 2; ++i)
        #pragma unroll
        for (int j = 0; j < 2; ++j) acc[i][j] = (f32x4)(0.f);

    int nt = HH / BK;                        // 16
    for (int tt = 0; tt < nt; ++tt) {
        int cur = tt % 3;
        if (tt + 1 < nt) {
            BSTAGE((tt + 1) % 3, (tt + 1) * BK);
            asm volatile("s_waitcnt vmcnt(2)" ::: "memory");
        } else {
            asm volatile("s_waitcnt vmcnt(0)" ::: "memory");
        }
        __builtin_amdgcn_s_barrier();
        __builtin_amdgcn_sched_barrier(0);
        __builtin_amdgcn_s_setprio(1);
        #pragma unroll
        for (int s2 = 0; s2 < 2; ++s2) {
            int k0 = tt * BK + s2 * 32;
            float4 wva = *(const float4*)&w1f[k0 + lk * 8];
            float4 wvb = *(const float4*)&w1f[k0 + lk * 8 + 4];
            float4 bva = *(const float4*)&b1f[k0 + lk * 8];
            float4 bvb = *(const float4*)&b1f[k0 + lk * 8 + 4];
            float wv[8] = {wva.x, wva.y, wva.z, wva.w, wvb.x, wvb.y, wvb.z, wvb.w};
            float bv2[8] = {bva.x, bva.y, bva.z, bva.w, bvb.x, bvb.y, bvb.z, bvb.w};
            ushort ahh[2][8], all2[2][8];
            #pragma unroll
            for (int mi = 0; mi < 2; ++mi) {
                float xm = mi ? x1 : x0;
                #pragma unroll
                for (int j = 0; j < 8; ++j) {
                    float h = fmaf(xm, wv[j], bv2[j]);
                    h = h > 0.f ? h : 0.f;
                    split_bf16(h, ahh[mi][j], all2[mi][j]);
                }
            }
            short8 bh2[2], bl2[2];
            #pragma unroll
            for (int ni = 0; ni < 2; ++ni) {
                bh2[ni] = *(const short8*)&Bb[cur][((wc * 2 + ni) * 2 + s2) * 512 + l * 8];
                bl2[ni] = *(const short8*)&Bb[cur][4096 + ((wc * 2 + ni) * 2 + s2) * 512 + l * 8];
            }
            #pragma unroll
            for (int mi = 0; mi < 2; ++mi) {
                short8 ah2 = *(short8*)ahh[mi];
                short8 al2 = *(short8*)all2[mi];
                #pragma unroll
                for (int ni = 0; ni < 2; ++ni) {
                    acc[mi][ni] = __builtin_amdgcn_mfma_f32_16x16x32_bf16(ah2, bh2[ni], acc[mi][ni], 0, 0, 0);
                    acc[mi][ni] = __builtin_amdgcn_mfma_f32_16x16x32_bf16(ah2, bl2[ni], acc[mi][ni], 0, 0, 0);
                    acc[mi][ni] = __builtin_amdgcn_mfma_f32_16x16x32_bf16(al2, bh2[ni], acc[mi][ni], 0, 0, 0);
                }
            }
        }
        __builtin_amdgcn_s_setprio(0);
        __builtin_amdgcn_sched_barrier(0);
    }
#undef BSTAGE

    float bv[2];
    #pragma unroll
    for (int ni = 0; ni < 2; ++ni) bv[ni] = b2[bn + wc * 32 + ni * 16 + lr];
    #pragma unroll
    for (int mi = 0; mi < 2; ++mi)
        #pragma unroll
        for (int ni = 0; ni < 2; ++ni)
            #pragma unroll
            for (int r = 0; r < 4; ++r) {
                int row = bm + wr * 32 + mi * 16 + lk * 4 + r;
                int col = bn + wc * 32 + ni * 16 + lr;
                float vv = acc[mi][ni][r] + bv[ni];
                vv = vv > 0.f ? vv : 0.f;
                unsigned short hi, lo;
                split_bf16(vv, hi, lo);
                Ch[(size_t)row * HH + col] = hi;
                Cl[(size_t)row * HH + col] = lo;
            }
}

// ======================================================================
// GEMM2: out[row] += (relu(h2 @ W3^T + b3)) . W4 via atomicAdd (ysum
// folded; out pre-initialized to b4[0] by pre_k). R15 structure.
// ======================================================================
__global__ __launch_bounds__(512, 2) void gemm2_k(
    const unsigned short* __restrict__ Ah, const unsigned short* __restrict__ Al,
    const unsigned short* __restrict__ Bh, const unsigned short* __restrict__ Bl,
    const float* __restrict__ b3,
    const float* __restrict__ W4, float* __restrict__ out)
{
    __shared__ unsigned short lds[3][24576];   // 144 KB
    int lin = blockIdx.x;
    int v = (lin & 7) * 32 + (lin >> 3);
    int bx = v >> 4, by = v & 15;
    int bm = bx * BM, bn = by * BN;
    int t = threadIdx.x, w = t >> 6, l = t & 63;
    int lr = l & 15, lk = l >> 4;
    int wr = w >> 1, wc = w & 1;

    size_t offA = (size_t)(bm + w * 16 + lr) * HH + lk * 8;
    size_t offB = (size_t)(bn + (w & 3) * 16 + lr) * HH + lk * 8;

#define STAGE(buf, k0)                                                          \
    do {                                                                        \
        unsigned short* L = lds[buf];                                           \
        gload16(Ah + offA + (k0),      L + (w * 2 + 0) * 512);                  \
        gload16(Ah + offA + (k0) + 32, L + (w * 2 + 1) * 512);                  \
        gload16(Al + offA + (k0),      L + 8192 + (w * 2 + 0) * 512);           \
        gload16(Al + offA + (k0) + 32, L + 8192 + (w * 2 + 1) * 512);           \
        if (w < 4) {                                                            \
            gload16(Bh + offB + (k0),      L + 16384 + ((w & 3) * 2 + 0) * 512);\
            gload16(Bh + offB + (k0) + 32, L + 16384 + ((w & 3) * 2 + 1) * 512);\
        } else {                                                                \
            gload16(Bl + offB + (k0),      L + 20480 + ((w & 3) * 2 + 0) * 512);\
            gload16(Bl + offB + (k0) + 32, L + 20480 + ((w & 3) * 2 + 1) * 512);\
        }                                                                       \
    } while (0)

    f32x4 acc[2][2];
    #pragma unroll
    for (int i = 0; i < 2; ++i)
        #pragma unroll
        for (int j = 0; j < 2; ++j) acc[i][j] = (f32x4)(0.f);

    STAGE(0, 0);

    int nt = HH / BK;                      // 16 steps
    for (int tt = 0; tt < nt; ++tt) {
        int cur = tt % 3;
        if (tt + 1 < nt) {
            STAGE((tt + 1) % 3, (tt + 1) * BK);
            asm volatile("s_waitcnt vmcnt(6)" ::: "memory");
        } else {
            asm volatile("s_waitcnt vmcnt(0)" ::: "memory");
        }
        __builtin_amdgcn_s_barrier();
        __builtin_amdgcn_sched_barrier(0);
        __builtin_amdgcn_s_setprio(1);
        unsigned short* L = lds[cur];
        #pragma unroll
        for (int s2 = 0; s2 < 2; ++s2) {
            short8 ah2[2], al2[2], bh2[2], bl2[2];
            #pragma unroll
            for (int mi = 0; mi < 2; ++mi) {
                ah2[mi] = *(const short8*)&L[((wr * 2 + mi) * 2 + s2) * 512 + l * 8];
                al2[mi] = *(const short8*)&L[8192 + ((wr * 2 + mi) * 2 + s2) * 512 + l * 8];
            }
            #pragma unroll
            for (int ni = 0; ni < 2; ++ni) {
                bh2[ni] = *(const short8*)&L[16384 + ((wc * 2 + ni) * 2 + s2) * 512 + l * 8];
                bl2[ni] = *(const short8*)&L[20480 + ((wc * 2 + ni) * 2 + s2) * 512 + l * 8];
            }
            #pragma unroll
            for (int mi = 0; mi < 2; ++mi)
                #pragma unroll
                for (int ni = 0; ni < 2; ++ni) {
                    acc[mi][ni] = __builtin_amdgcn_mfma_f32_16x16x32_bf16(ah2[mi], bh2[ni], acc[mi][ni], 0, 0, 0);
                    acc[mi][ni] = __builtin_amdgcn_mfma_f32_16x16x32_bf16(ah2[mi], bl2[ni], acc[mi][ni], 0, 0, 0);
                    acc[mi][ni] = __builtin_amdgcn_mfma_f32_16x16x32_bf16(al2[mi], bh2[ni], acc[mi][ni], 0, 0, 0);
                }
        }
        __builtin_amdgcn_s_setprio(0);
        __builtin_amdgcn_sched_barrier(0);
    }
#undef STAGE

    // epilogue: fused W4 dots -> atomicAdd into out
    float bv[2], w4v[2];
    #pragma unroll
    for (int ni = 0; ni < 2; ++ni) {
        bv[ni]  = b3[bn + wc * 32 + ni * 16 + lr];
        w4v[ni] = W4[bn + wc * 32 + ni * 16 + lr];
    }
    #pragma unroll
    for (int mi = 0; mi < 2; ++mi) {
        float ps[4];
        #pragma unroll
        for (int r = 0; r < 4; ++r) {
            float acc_d = 0.f;
            #pragma unroll
            for (int ni = 0; ni < 2; ++ni) {
                float vv = acc[mi][ni][r] + bv[ni];
                vv = vv > 0.f ? vv : 0.f;
                acc_d += vv * w4v[ni];
            }
            ps[r] = acc_d;
        }
        #pragma unroll
        for (int r = 0; r < 4; ++r) {
            #pragma unroll
            for (int m2 = 1; m2 < 16; m2 <<= 1) ps[r] += __shfl_xor(ps[r], m2, 64);
        }
        if (lr == 0) {
            #pragma unroll
            for (int r = 0; r < 4; ++r) {
                int row = bm + wr * 32 + mi * 16 + lk * 4 + r;
                atomicAdd(&out[row], ps[r]);
            }
        }
    }
}

extern "C" void kernel_launch(void* const* d_in, const int* in_sizes, int n_in,
                              void* d_out, int out_size, void* d_ws, size_t ws_size,
                              hipStream_t stream) {
    const float* X  = (const float*)d_in[0];
    const int*   p  = (const int*)d_in[1];
    const float* W1 = (const float*)d_in[2];
    const float* b1 = (const float*)d_in[3];
    const float* W2 = (const float*)d_in[4];
    const float* b2 = (const float*)d_in[5];
    const float* W3 = (const float*)d_in[6];
    const float* b3 = (const float*)d_in[7];
    const float* W4 = (const float*)d_in[8];
    const float* b4 = (const float*)d_in[9];
    float* out = (float*)d_out;

    char* ws = (char*)d_ws;
    size_t off = 0;
    float* psum = (float*)(ws + off); off += (size_t)NCH * PP * 4;
    unsigned short* h2h = (unsigned short*)(ws + off); off += (size_t)PP * HH * 2;
    unsigned short* h2l = (unsigned short*)(ws + off); off += (size_t)PP * HH * 2;
    unsigned short* w2h = (unsigned short*)(ws + off); off += (size_t)HH * HH * 2;
    unsigned short* w2l = (unsigned short*)(ws + off); off += (size_t)HH * HH * 2;
    unsigned short* w3h = (unsigned short*)(ws + off); off += (size_t)HH * HH * 2;
    unsigned short* w3l = (unsigned short*)(ws + off); off += (size_t)HH * HH * 2;

    pre_k<<<776, 256, 0, stream>>>(X, p, psum, W2, w2h, w2l, b4, out);
    pre3_k<<<256, 256, 0, stream>>>(W3, w3h, w3l);
    gemm1_k<<<256, 512, 0, stream>>>(psum, W1, b1, w2h, w2l, b2, h2h, h2l);
    gemm2_k<<<256, 512, 0, stream>>>(h2h, h2l, w3h, w3l, b3, W4, out);
}

// Round 20
// 81.228 us; speedup vs baseline: 2.2792x; 1.0113x over previous
//
#include <hip/hip_runtime.h>
#include <hip/hip_bf16.h>

#define CC 20480      // columns of X
#define PP 2048       // P
#define NROWS 2047    // rows reduced
#define SRR 10
#define HH 1024
#define NCH 128       // row chunks (16 rows each) — 2x TLP vs R15

typedef __attribute__((ext_vector_type(8))) short short8;
typedef __attribute__((ext_vector_type(4))) float f32x4;

// ---------------- split helper ----------------------------------------
__device__ __forceinline__ void split_bf16(float v, unsigned short& hi, unsigned short& lo) {
    __hip_bfloat16 h = __float2bfloat16(v);
    float r = v - __bfloat162float(h);
    __hip_bfloat16 l2 = __float2bfloat16(r);
    hi = *(unsigned short*)&h;
    lo = *(unsigned short*)&l2;
}

// ---------------- pre: colsum (0..1023) + W2 split + W3 split ----------
__global__ __launch_bounds__(256) void pre_k(const float* __restrict__ X,
                                             const int* __restrict__ p,
                                             float* __restrict__ psum,
                                             const float* __restrict__ W2,
                                             unsigned short* __restrict__ w2h,
                                             unsigned short* __restrict__ w2l,
                                             const float* __restrict__ W3,
                                             unsigned short* __restrict__ w3h,
                                             unsigned short* __restrict__ w3l) {
    int b = blockIdx.x, t = threadIdx.x;
    if (b < 1024) {
        int k = (b & 7) * 256 + t;              // 0..2047
        int chunk = b >> 3;                     // 0..127
        int r0 = chunk * 16;
        int r1 = r0 + 16; if (r1 > NROWS) r1 = NROWS;
        float s = 0.f;
        int base = SRR * k;
        for (int i = r0; i < r1; ++i) {
            int col = base - p[i]; if (col < 0) col += CC;   // p[i] in [0,64)
            s += X[(size_t)i * (size_t)(SRR * CC) + col];
        }
        psum[chunk * PP + k] = s;
        return;
    }
    int bb = b - 1024;
    const float* src; unsigned short *dh, *dl;
    if (bb < 256) { src = W2; dh = w2h; dl = w2l; }
    else { src = W3; dh = w3h; dl = w3l; bb -= 256; }
    int idx = bb * 4096 + t * 16;
    #pragma unroll
    for (int q = 0; q < 4; ++q) {
        float4 v = *(const float4*)&src[idx + q * 4];
        float vv[4] = {v.x, v.y, v.z, v.w};
        ushort hi4[4], lo4[4];
        #pragma unroll
        for (int i = 0; i < 4; ++i) split_bf16(vv[i], hi4[i], lo4[i]);
        *(ushort4*)&dh[idx + q * 4] = *(ushort4*)hi4;
        *(ushort4*)&dl[idx + q * 4] = *(ushort4*)lo4;
    }
}

// ---------------- async global->LDS, 16B/lane -------------------------
__device__ __forceinline__ void gload16(const unsigned short* g, unsigned short* lds) {
    __builtin_amdgcn_global_load_lds(
        (const __attribute__((address_space(1))) void*)g,
        (__attribute__((address_space(3))) void*)lds,
        16, 0, 0);
}

#define BM 128
#define BN 64
#define BK 64

// ======================================================================
// GEMM1: h2 = relu(h1 @ W2^T + b2), h1 = relu(x*W1+b1) on the fly.
// B via global_load_lds, BK=64, triple-buffered, 1 barrier + vmcnt(2)
// per step (R15 structure, 80.2 us best).
// ======================================================================
__global__ __launch_bounds__(512, 2) void gemm1_k(
    const float* __restrict__ psum,
    const float* __restrict__ W1, const float* __restrict__ b1,
    const unsigned short* __restrict__ Bh, const unsigned short* __restrict__ Bl,
    const float* __restrict__ b2,
    unsigned short* __restrict__ Ch, unsigned short* __restrict__ Cl)
{
    __shared__ unsigned short Bb[3][8192];   // per buf: hi [0,4096), lo [4096,8192)
    __shared__ float w1f[1024], b1f[1024], xv[128];

    int lin = blockIdx.x, t = threadIdx.x;
    int v = (lin & 7) * 32 + (lin >> 3);     // XCD-chunked, grid=256
    int bx = v >> 4, by = v & 15;
    int bm = bx * BM, bn = by * BN;
    int w = t >> 6, l = t & 63;
    int lr = l & 15, lk = l >> 4;
    int wr = w >> 1, wc = w & 1;

    size_t offB = (size_t)(bn + (w >> 1) * 16 + lr) * HH + (w & 1) * 32 + lk * 8;
#define BSTAGE(buf, k0)                                         \
    do {                                                        \
        gload16(Bh + offB + (k0), Bb[buf] + w * 512);           \
        gload16(Bl + offB + (k0), Bb[buf] + 4096 + w * 512);    \
    } while (0)

    BSTAGE(0, 0);
    // ---- prologue: xv, W1/b1 to LDS ----
    {
        int row = t >> 2, q = t & 3;
        float s = 0.f;
        #pragma unroll
        for (int j = 0; j < 32; ++j) s += psum[(q * 32 + j) * PP + bm + row];
        s += __shfl_xor(s, 1, 64);
        s += __shfl_xor(s, 2, 64);
        if (q == 0) xv[row] = s * (1.0f / (float)NROWS);
        if (t < 256) *(float4*)&w1f[t * 4] = *(const float4*)&W1[t * 4];
        else *(float4*)&b1f[(t - 256) * 4] = *(const float4*)&b1[(t - 256) * 4];
    }
    __syncthreads();

    float x0 = xv[wr * 32 + lr], x1 = xv[wr * 32 + 16 + lr];

    f32x4 acc[2][2];
    #pragma unroll
    for (int i = 0; i < 2; ++i)
        #pragma unroll
        for (int j = 0; j < 2; ++j) acc[i][j] = (f32x4)(0.f);

    int nt = HH / BK;                        // 16
    for (int tt = 0; tt < nt; ++tt) {
        int cur = tt % 3;
        if (tt + 1 < nt) {
            BSTAGE((tt + 1) % 3, (tt + 1) * BK);
            asm volatile("s_waitcnt vmcnt(2)" ::: "memory");
        } else {
            asm volatile("s_waitcnt vmcnt(0)" ::: "memory");
        }
        __builtin_amdgcn_s_barrier();
        __builtin_amdgcn_sched_barrier(0);
        __builtin_amdgcn_s_setprio(1);
        #pragma unroll
        for (int s2 = 0; s2 < 2; ++s2) {
            int k0 = tt * BK + s2 * 32;
            float4 wva = *(const float4*)&w1f[k0 + lk * 8];
            float4 wvb = *(const float4*)&w1f[k0 + lk * 8 + 4];
            float4 bva = *(const float4*)&b1f[k0 + lk * 8];
            float4 bvb = *(const float4*)&b1f[k0 + lk * 8 + 4];
            float wv[8] = {wva.x, wva.y, wva.z, wva.w, wvb.x, wvb.y, wvb.z, wvb.w};
            float bv2[8] = {bva.x, bva.y, bva.z, bva.w, bvb.x, bvb.y, bvb.z, bvb.w};
            ushort ahh[2][8], all2[2][8];
            #pragma unroll
            for (int mi = 0; mi < 2; ++mi) {
                float xm = mi ? x1 : x0;
                #pragma unroll
                for (int j = 0; j < 8; ++j) {
                    float h = fmaf(xm, wv[j], bv2[j]);
                    h = h > 0.f ? h : 0.f;
                    split_bf16(h, ahh[mi][j], all2[mi][j]);
                }
            }
            short8 bh2[2], bl2[2];
            #pragma unroll
            for (int ni = 0; ni < 2; ++ni) {
                bh2[ni] = *(const short8*)&Bb[cur][((wc * 2 + ni) * 2 + s2) * 512 + l * 8];
                bl2[ni] = *(const short8*)&Bb[cur][4096 + ((wc * 2 + ni) * 2 + s2) * 512 + l * 8];
            }
            #pragma unroll
            for (int mi = 0; mi < 2; ++mi) {
                short8 ah2 = *(short8*)ahh[mi];
                short8 al2 = *(short8*)all2[mi];
                #pragma unroll
                for (int ni = 0; ni < 2; ++ni) {
                    acc[mi][ni] = __builtin_amdgcn_mfma_f32_16x16x32_bf16(ah2, bh2[ni], acc[mi][ni], 0, 0, 0);
                    acc[mi][ni] = __builtin_amdgcn_mfma_f32_16x16x32_bf16(ah2, bl2[ni], acc[mi][ni], 0, 0, 0);
                    acc[mi][ni] = __builtin_amdgcn_mfma_f32_16x16x32_bf16(al2, bh2[ni], acc[mi][ni], 0, 0, 0);
                }
            }
        }
        __builtin_amdgcn_s_setprio(0);
        __builtin_amdgcn_sched_barrier(0);
    }
#undef BSTAGE

    float bv[2];
    #pragma unroll
    for (int ni = 0; ni < 2; ++ni) bv[ni] = b2[bn + wc * 32 + ni * 16 + lr];
    #pragma unroll
    for (int mi = 0; mi < 2; ++mi)
        #pragma unroll
        for (int ni = 0; ni < 2; ++ni)
            #pragma unroll
            for (int r = 0; r < 4; ++r) {
                int row = bm + wr * 32 + mi * 16 + lk * 4 + r;
                int col = bn + wc * 32 + ni * 16 + lr;
                float vv = acc[mi][ni][r] + bv[ni];
                vv = vv > 0.f ? vv : 0.f;
                unsigned short hi, lo;
                split_bf16(vv, hi, lo);
                Ch[(size_t)row * HH + col] = hi;
                Cl[(size_t)row * HH + col] = lo;
            }
}

// ======================================================================
// GEMM2: partial = (relu(h2 @ W3^T + b3)) . W4 fused. A,B via
// global_load_lds, BK=64, triple-buffered (144 KB LDS), 1 barrier +
// vmcnt(6) per step, 16 steps (R15 structure).
// ======================================================================
__global__ __launch_bounds__(512, 2) void gemm2_k(
    const unsigned short* __restrict__ Ah, const unsigned short* __restrict__ Al,
    const unsigned short* __restrict__ Bh, const unsigned short* __restrict__ Bl,
    const float* __restrict__ b3,
    const float* __restrict__ W4, float* __restrict__ partial)
{
    __shared__ unsigned short lds[3][24576];   // 144 KB
    int lin = blockIdx.x;
    int v = (lin & 7) * 32 + (lin >> 3);
    int bx = v >> 4, by = v & 15;
    int bm = bx * BM, bn = by * BN;
    int t = threadIdx.x, w = t >> 6, l = t & 63;
    int lr = l & 15, lk = l >> 4;
    int wr = w >> 1, wc = w & 1;

    size_t offA = (size_t)(bm + w * 16 + lr) * HH + lk * 8;
    size_t offB = (size_t)(bn + (w & 3) * 16 + lr) * HH + lk * 8;

#define STAGE(buf, k0)                                                          \
    do {                                                                        \
        unsigned short* L = lds[buf];                                           \
        gload16(Ah + offA + (k0),      L + (w * 2 + 0) * 512);                  \
        gload16(Ah + offA + (k0) + 32, L + (w * 2 + 1) * 512);                  \
        gload16(Al + offA + (k0),      L + 8192 + (w * 2 + 0) * 512);           \
        gload16(Al + offA + (k0) + 32, L + 8192 + (w * 2 + 1) * 512);           \
        if (w < 4) {                                                            \
            gload16(Bh + offB + (k0),      L + 16384 + ((w & 3) * 2 + 0) * 512);\
            gload16(Bh + offB + (k0) + 32, L + 16384 + ((w & 3) * 2 + 1) * 512);\
        } else {                                                                \
            gload16(Bl + offB + (k0),      L + 20480 + ((w & 3) * 2 + 0) * 512);\
            gload16(Bl + offB + (k0) + 32, L + 20480 + ((w & 3) * 2 + 1) * 512);\
        }                                                                       \
    } while (0)

    f32x4 acc[2][2];
    #pragma unroll
    for (int i = 0; i < 2; ++i)
        #pragma unroll
        for (int j = 0; j < 2; ++j) acc[i][j] = (f32x4)(0.f);

    STAGE(0, 0);

    int nt = HH / BK;                      // 16 steps
    for (int tt = 0; tt < nt; ++tt) {
        int cur = tt % 3;
        if (tt + 1 < nt) {
            STAGE((tt + 1) % 3, (tt + 1) * BK);
            asm volatile("s_waitcnt vmcnt(6)" ::: "memory");
        } else {
            asm volatile("s_waitcnt vmcnt(0)" ::: "memory");
        }
        __builtin_amdgcn_s_barrier();
        __builtin_amdgcn_sched_barrier(0);
        __builtin_amdgcn_s_setprio(1);
        unsigned short* L = lds[cur];
        #pragma unroll
        for (int s2 = 0; s2 < 2; ++s2) {
            short8 ah2[2], al2[2], bh2[2], bl2[2];
            #pragma unroll
            for (int mi = 0; mi < 2; ++mi) {
                ah2[mi] = *(const short8*)&L[((wr * 2 + mi) * 2 + s2) * 512 + l * 8];
                al2[mi] = *(const short8*)&L[8192 + ((wr * 2 + mi) * 2 + s2) * 512 + l * 8];
            }
            #pragma unroll
            for (int ni = 0; ni < 2; ++ni) {
                bh2[ni] = *(const short8*)&L[16384 + ((wc * 2 + ni) * 2 + s2) * 512 + l * 8];
                bl2[ni] = *(const short8*)&L[20480 + ((wc * 2 + ni) * 2 + s2) * 512 + l * 8];
            }
            #pragma unroll
            for (int mi = 0; mi < 2; ++mi)
                #pragma unroll
                for (int ni = 0; ni < 2; ++ni) {
                    acc[mi][ni] = __builtin_amdgcn_mfma_f32_16x16x32_bf16(ah2[mi], bh2[ni], acc[mi][ni], 0, 0, 0);
                    acc[mi][ni] = __builtin_amdgcn_mfma_f32_16x16x32_bf16(ah2[mi], bl2[ni], acc[mi][ni], 0, 0, 0);
                    acc[mi][ni] = __builtin_amdgcn_mfma_f32_16x16x32_bf16(al2[mi], bh2[ni], acc[mi][ni], 0, 0, 0);
                }
        }
        __builtin_amdgcn_s_setprio(0);
        __builtin_amdgcn_sched_barrier(0);
    }
#undef STAGE

    // epilogue: fused W4 partial dots
    float bv[2], w4v[2];
    #pragma unroll
    for (int ni = 0; ni < 2; ++ni) {
        bv[ni]  = b3[bn + wc * 32 + ni * 16 + lr];
        w4v[ni] = W4[bn + wc * 32 + ni * 16 + lr];
    }
    #pragma unroll
    for (int mi = 0; mi < 2; ++mi) {
        float ps[4];
        #pragma unroll
        for (int r = 0; r < 4; ++r) {
            float acc_d = 0.f;
            #pragma unroll
            for (int ni = 0; ni < 2; ++ni) {
                float vv = acc[mi][ni][r] + bv[ni];
                vv = vv > 0.f ? vv : 0.f;
                acc_d += vv * w4v[ni];
            }
            ps[r] = acc_d;
        }
        #pragma unroll
        for (int r = 0; r < 4; ++r) {
            #pragma unroll
            for (int m2 = 1; m2 < 16; m2 <<= 1) ps[r] += __shfl_xor(ps[r], m2, 64);
        }
        if (lr == 0) {
            #pragma unroll
            for (int r = 0; r < 4; ++r) {
                int row = bm + wr * 32 + mi * 16 + lk * 4 + r;
                partial[(size_t)row * 32 + by * 2 + wc] = ps[r];
            }
        }
    }
}

// ---------------- ysum: y[r] = sum(partial[r][:]) + b4 ----------------
__global__ __launch_bounds__(256) void ysum_k(const float* __restrict__ partial,
                                              const float* __restrict__ b4,
                                              float* __restrict__ y) {
    int r = blockIdx.x * 256 + threadIdx.x;
    float s = 0.f;
    #pragma unroll
    for (int q = 0; q < 8; ++q) {
        float4 v = *(const float4*)&partial[(size_t)r * 32 + q * 4];
        s += v.x + v.y + v.z + v.w;
    }
    y[r] = s + b4[0];
}

extern "C" void kernel_launch(void* const* d_in, const int* in_sizes, int n_in,
                              void* d_out, int out_size, void* d_ws, size_t ws_size,
                              hipStream_t stream) {
    const float* X  = (const float*)d_in[0];
    const int*   p  = (const int*)d_in[1];
    const float* W1 = (const float*)d_in[2];
    const float* b1 = (const float*)d_in[3];
    const float* W2 = (const float*)d_in[4];
    const float* b2 = (const float*)d_in[5];
    const float* W3 = (const float*)d_in[6];
    const float* b3 = (const float*)d_in[7];
    const float* W4 = (const float*)d_in[8];
    const float* b4 = (const float*)d_in[9];
    float* out = (float*)d_out;

    char* ws = (char*)d_ws;
    size_t off = 0;
    float* psum = (float*)(ws + off); off += (size_t)NCH * PP * 4;
    unsigned short* h2h = (unsigned short*)(ws + off); off += (size_t)PP * HH * 2;
    unsigned short* h2l = (unsigned short*)(ws + off); off += (size_t)PP * HH * 2;
    unsigned short* w2h = (unsigned short*)(ws + off); off += (size_t)HH * HH * 2;
    unsigned short* w2l = (unsigned short*)(ws + off); off += (size_t)HH * HH * 2;
    unsigned short* w3h = (unsigned short*)(ws + off); off += (size_t)HH * HH * 2;
    unsigned short* w3l = (unsigned short*)(ws + off); off += (size_t)HH * HH * 2;
    float* partial = (float*)(ws + off); off += (size_t)PP * 32 * 4;

    pre_k<<<1536, 256, 0, stream>>>(X, p, psum, W2, w2h, w2l, W3, w3h, w3l);
    gemm1_k<<<256, 512, 0, stream>>>(psum, W1, b1, w2h, w2l, b2, h2h, h2l);
    gemm2_k<<<256, 512, 0, stream>>>(h2h, h2l, w3h, w3l, b3, W4, partial);
    ysum_k<<<PP / 256, 256, 0, stream>>>(partial, b4, out);
}

// Round 21
// 80.335 us; speedup vs baseline: 2.3046x; 1.0111x over previous
//
#include <hip/hip_runtime.h>
#include <hip/hip_bf16.h>

#define CC 20480      // columns of X
#define PP 2048       // P
#define NROWS 2047    // rows reduced
#define SRR 10
#define HH 1024
#define NCH 64        // row chunks (32 rows each)

typedef __attribute__((ext_vector_type(8))) short short8;
typedef __attribute__((ext_vector_type(4))) float f32x4;

// ---------------- split helper ----------------------------------------
__device__ __forceinline__ void split_bf16(float v, unsigned short& hi, unsigned short& lo) {
    __hip_bfloat16 h = __float2bfloat16(v);
    float r = v - __bfloat162float(h);
    __hip_bfloat16 l2 = __float2bfloat16(r);
    hi = *(unsigned short*)&h;
    lo = *(unsigned short*)&l2;
}

// ---------------- pre: colsum (0..511) + W2 split + W3 split -----------
__global__ __launch_bounds__(256) void pre_k(const float* __restrict__ X,
                                             const int* __restrict__ p,
                                             float* __restrict__ psum,
                                             const float* __restrict__ W2,
                                             unsigned short* __restrict__ w2h,
                                             unsigned short* __restrict__ w2l,
                                             const float* __restrict__ W3,
                                             unsigned short* __restrict__ w3h,
                                             unsigned short* __restrict__ w3l) {
    int b = blockIdx.x, t = threadIdx.x;
    if (b < 512) {
        int k = (b & 7) * 256 + t;              // 0..2047
        int chunk = b >> 3;                     // 0..63
        int r0 = chunk * 32;
        int r1 = r0 + 32; if (r1 > NROWS) r1 = NROWS;
        float s = 0.f;
        int base = SRR * k;
        for (int i = r0; i < r1; ++i) {
            int col = base - p[i]; if (col < 0) col += CC;   // p[i] in [0,64)
            s += X[(size_t)i * (size_t)(SRR * CC) + col];
        }
        psum[chunk * PP + k] = s;
        return;
    }
    int bb = b - 512;
    const float* src; unsigned short *dh, *dl;
    if (bb < 256) { src = W2; dh = w2h; dl = w2l; }
    else { src = W3; dh = w3h; dl = w3l; bb -= 256; }
    int idx = bb * 4096 + t * 16;
    #pragma unroll
    for (int q = 0; q < 4; ++q) {
        float4 v = *(const float4*)&src[idx + q * 4];
        float vv[4] = {v.x, v.y, v.z, v.w};
        ushort hi4[4], lo4[4];
        #pragma unroll
        for (int i = 0; i < 4; ++i) split_bf16(vv[i], hi4[i], lo4[i]);
        *(ushort4*)&dh[idx + q * 4] = *(ushort4*)hi4;
        *(ushort4*)&dl[idx + q * 4] = *(ushort4*)lo4;
    }
}

// ---------------- async global->LDS, 16B/lane -------------------------
__device__ __forceinline__ void gload16(const unsigned short* g, unsigned short* lds) {
    __builtin_amdgcn_global_load_lds(
        (const __attribute__((address_space(1))) void*)g,
        (__attribute__((address_space(3))) void*)lds,
        16, 0, 0);
}

#define BM 128
#define BN 64
#define BK 64

// ======================================================================
// GEMM1: h2 = relu(h1 @ W2^T + b2), h1 = relu(x*W1+b1) on the fly.
// B via global_load_lds, BK=64, triple-buffered, 1 barrier + vmcnt(2)
// per step (R15 structure, 80.2 us best).
// ======================================================================
__global__ __launch_bounds__(512, 2) void gemm1_k(
    const float* __restrict__ psum,
    const float* __restrict__ W1, const float* __restrict__ b1,
    const unsigned short* __restrict__ Bh, const unsigned short* __restrict__ Bl,
    const float* __restrict__ b2,
    unsigned short* __restrict__ Ch, unsigned short* __restrict__ Cl)
{
    __shared__ unsigned short Bb[3][8192];   // per buf: hi [0,4096), lo [4096,8192)
    __shared__ float w1f[1024], b1f[1024], xv[128];

    int lin = blockIdx.x, t = threadIdx.x;
    int v = (lin & 7) * 32 + (lin >> 3);     // XCD-chunked, grid=256
    int bx = v >> 4, by = v & 15;
    int bm = bx * BM, bn = by * BN;
    int w = t >> 6, l = t & 63;
    int lr = l & 15, lk = l >> 4;
    int wr = w >> 1, wc = w & 1;

    size_t offB = (size_t)(bn + (w >> 1) * 16 + lr) * HH + (w & 1) * 32 + lk * 8;
#define BSTAGE(buf, k0)                                         \
    do {                                                        \
        gload16(Bh + offB + (k0), Bb[buf] + w * 512);           \
        gload16(Bl + offB + (k0), Bb[buf] + 4096 + w * 512);    \
    } while (0)

    BSTAGE(0, 0);
    // ---- prologue: xv, W1/b1 to LDS ----
    {
        int row = t >> 2, q = t & 3;
        float s = 0.f;
        #pragma unroll
        for (int j = 0; j < 16; ++j) s += psum[(q * 16 + j) * PP + bm + row];
        s += __shfl_xor(s, 1, 64);
        s += __shfl_xor(s, 2, 64);
        if (q == 0) xv[row] = s * (1.0f / (float)NROWS);
        if (t < 256) *(float4*)&w1f[t * 4] = *(const float4*)&W1[t * 4];
        else *(float4*)&b1f[(t - 256) * 4] = *(const float4*)&b1[(t - 256) * 4];
    }
    __syncthreads();

    float x0 = xv[wr * 32 + lr], x1 = xv[wr * 32 + 16 + lr];

    f32x4 acc[2][2];
    #pragma unroll
    for (int i = 0; i < 2; ++i)
        #pragma unroll
        for (int j = 0; j < 2; ++j) acc[i][j] = (f32x4)(0.f);

    int nt = HH / BK;                        // 16
    for (int tt = 0; tt < nt; ++tt) {
        int cur = tt % 3;
        if (tt + 1 < nt) {
            BSTAGE((tt + 1) % 3, (tt + 1) * BK);
            asm volatile("s_waitcnt vmcnt(2)" ::: "memory");
        } else {
            asm volatile("s_waitcnt vmcnt(0)" ::: "memory");
        }
        __builtin_amdgcn_s_barrier();
        __builtin_amdgcn_sched_barrier(0);
        __builtin_amdgcn_s_setprio(1);
        #pragma unroll
        for (int s2 = 0; s2 < 2; ++s2) {
            int k0 = tt * BK + s2 * 32;
            float4 wva = *(const float4*)&w1f[k0 + lk * 8];
            float4 wvb = *(const float4*)&w1f[k0 + lk * 8 + 4];
            float4 bva = *(const float4*)&b1f[k0 + lk * 8];
            float4 bvb = *(const float4*)&b1f[k0 + lk * 8 + 4];
            float wv[8] = {wva.x, wva.y, wva.z, wva.w, wvb.x, wvb.y, wvb.z, wvb.w};
            float bv2[8] = {bva.x, bva.y, bva.z, bva.w, bvb.x, bvb.y, bvb.z, bvb.w};
            ushort ahh[2][8], all2[2][8];
            #pragma unroll
            for (int mi = 0; mi < 2; ++mi) {
                float xm = mi ? x1 : x0;
                #pragma unroll
                for (int j = 0; j < 8; ++j) {
                    float h = fmaf(xm, wv[j], bv2[j]);
                    h = h > 0.f ? h : 0.f;
                    split_bf16(h, ahh[mi][j], all2[mi][j]);
                }
            }
            short8 bh2[2], bl2[2];
            #pragma unroll
            for (int ni = 0; ni < 2; ++ni) {
                bh2[ni] = *(const short8*)&Bb[cur][((wc * 2 + ni) * 2 + s2) * 512 + l * 8];
                bl2[ni] = *(const short8*)&Bb[cur][4096 + ((wc * 2 + ni) * 2 + s2) * 512 + l * 8];
            }
            #pragma unroll
            for (int mi = 0; mi < 2; ++mi) {
                short8 ah2 = *(short8*)ahh[mi];
                short8 al2 = *(short8*)all2[mi];
                #pragma unroll
                for (int ni = 0; ni < 2; ++ni) {
                    acc[mi][ni] = __builtin_amdgcn_mfma_f32_16x16x32_bf16(ah2, bh2[ni], acc[mi][ni], 0, 0, 0);
                    acc[mi][ni] = __builtin_amdgcn_mfma_f32_16x16x32_bf16(ah2, bl2[ni], acc[mi][ni], 0, 0, 0);
                    acc[mi][ni] = __builtin_amdgcn_mfma_f32_16x16x32_bf16(al2, bh2[ni], acc[mi][ni], 0, 0, 0);
                }
            }
        }
        __builtin_amdgcn_s_setprio(0);
        __builtin_amdgcn_sched_barrier(0);
    }
#undef BSTAGE

    float bv[2];
    #pragma unroll
    for (int ni = 0; ni < 2; ++ni) bv[ni] = b2[bn + wc * 32 + ni * 16 + lr];
    #pragma unroll
    for (int mi = 0; mi < 2; ++mi)
        #pragma unroll
        for (int ni = 0; ni < 2; ++ni)
            #pragma unroll
            for (int r = 0; r < 4; ++r) {
                int row = bm + wr * 32 + mi * 16 + lk * 4 + r;
                int col = bn + wc * 32 + ni * 16 + lr;
                float vv = acc[mi][ni][r] + bv[ni];
                vv = vv > 0.f ? vv : 0.f;
                unsigned short hi, lo;
                split_bf16(vv, hi, lo);
                Ch[(size_t)row * HH + col] = hi;
                Cl[(size_t)row * HH + col] = lo;
            }
}

// ======================================================================
// GEMM2: partial = (relu(h2 @ W3^T + b3)) . W4 fused. A,B via
// global_load_lds, BK=64, triple-buffered (144 KB LDS), 1 barrier +
// vmcnt(6) per step, 16 steps (R15 structure).
// ======================================================================
__global__ __launch_bounds__(512, 2) void gemm2_k(
    const unsigned short* __restrict__ Ah, const unsigned short* __restrict__ Al,
    const unsigned short* __restrict__ Bh, const unsigned short* __restrict__ Bl,
    const float* __restrict__ b3,
    const float* __restrict__ W4, float* __restrict__ partial)
{
    __shared__ unsigned short lds[3][24576];   // 144 KB
    int lin = blockIdx.x;
    int v = (lin & 7) * 32 + (lin >> 3);
    int bx = v >> 4, by = v & 15;
    int bm = bx * BM, bn = by * BN;
    int t = threadIdx.x, w = t >> 6, l = t & 63;
    int lr = l & 15, lk = l >> 4;
    int wr = w >> 1, wc = w & 1;

    size_t offA = (size_t)(bm + w * 16 + lr) * HH + lk * 8;
    size_t offB = (size_t)(bn + (w & 3) * 16 + lr) * HH + lk * 8;

#define STAGE(buf, k0)                                                          \
    do {                                                                        \
        unsigned short* L = lds[buf];                                           \
        gload16(Ah + offA + (k0),      L + (w * 2 + 0) * 512);                  \
        gload16(Ah + offA + (k0) + 32, L + (w * 2 + 1) * 512);                  \
        gload16(Al + offA + (k0),      L + 8192 + (w * 2 + 0) * 512);           \
        gload16(Al + offA + (k0) + 32, L + 8192 + (w * 2 + 1) * 512);           \
        if (w < 4) {                                                            \
            gload16(Bh + offB + (k0),      L + 16384 + ((w & 3) * 2 + 0) * 512);\
            gload16(Bh + offB + (k0) + 32, L + 16384 + ((w & 3) * 2 + 1) * 512);\
        } else {                                                                \
            gload16(Bl + offB + (k0),      L + 20480 + ((w & 3) * 2 + 0) * 512);\
            gload16(Bl + offB + (k0) + 32, L + 20480 + ((w & 3) * 2 + 1) * 512);\
        }                                                                       \
    } while (0)

    f32x4 acc[2][2];
    #pragma unroll
    for (int i = 0; i < 2; ++i)
        #pragma unroll
        for (int j = 0; j < 2; ++j) acc[i][j] = (f32x4)(0.f);

    STAGE(0, 0);

    int nt = HH / BK;                      // 16 steps
    for (int tt = 0; tt < nt; ++tt) {
        int cur = tt % 3;
        if (tt + 1 < nt) {
            STAGE((tt + 1) % 3, (tt + 1) * BK);
            asm volatile("s_waitcnt vmcnt(6)" ::: "memory");
        } else {
            asm volatile("s_waitcnt vmcnt(0)" ::: "memory");
        }
        __builtin_amdgcn_s_barrier();
        __builtin_amdgcn_sched_barrier(0);
        __builtin_amdgcn_s_setprio(1);
        unsigned short* L = lds[cur];
        #pragma unroll
        for (int s2 = 0; s2 < 2; ++s2) {
            short8 ah2[2], al2[2], bh2[2], bl2[2];
            #pragma unroll
            for (int mi = 0; mi < 2; ++mi) {
                ah2[mi] = *(const short8*)&L[((wr * 2 + mi) * 2 + s2) * 512 + l * 8];
                al2[mi] = *(const short8*)&L[8192 + ((wr * 2 + mi) * 2 + s2) * 512 + l * 8];
            }
            #pragma unroll
            for (int ni = 0; ni < 2; ++ni) {
                bh2[ni] = *(const short8*)&L[16384 + ((wc * 2 + ni) * 2 + s2) * 512 + l * 8];
                bl2[ni] = *(const short8*)&L[20480 + ((wc * 2 + ni) * 2 + s2) * 512 + l * 8];
            }
            #pragma unroll
            for (int mi = 0; mi < 2; ++mi)
                #pragma unroll
                for (int ni = 0; ni < 2; ++ni) {
                    acc[mi][ni] = __builtin_amdgcn_mfma_f32_16x16x32_bf16(ah2[mi], bh2[ni], acc[mi][ni], 0, 0, 0);
                    acc[mi][ni] = __builtin_amdgcn_mfma_f32_16x16x32_bf16(ah2[mi], bl2[ni], acc[mi][ni], 0, 0, 0);
                    acc[mi][ni] = __builtin_amdgcn_mfma_f32_16x16x32_bf16(al2[mi], bh2[ni], acc[mi][ni], 0, 0, 0);
                }
        }
        __builtin_amdgcn_s_setprio(0);
        __builtin_amdgcn_sched_barrier(0);
    }
#undef STAGE

    // epilogue: fused W4 partial dots
    float bv[2], w4v[2];
    #pragma unroll
    for (int ni = 0; ni < 2; ++ni) {
        bv[ni]  = b3[bn + wc * 32 + ni * 16 + lr];
        w4v[ni] = W4[bn + wc * 32 + ni * 16 + lr];
    }
    #pragma unroll
    for (int mi = 0; mi < 2; ++mi) {
        float ps[4];
        #pragma unroll
        for (int r = 0; r < 4; ++r) {
            float acc_d = 0.f;
            #pragma unroll
            for (int ni = 0; ni < 2; ++ni) {
                float vv = acc[mi][ni][r] + bv[ni];
                vv = vv > 0.f ? vv : 0.f;
                acc_d += vv * w4v[ni];
            }
            ps[r] = acc_d;
        }
        #pragma unroll
        for (int r = 0; r < 4; ++r) {
            #pragma unroll
            for (int m2 = 1; m2 < 16; m2 <<= 1) ps[r] += __shfl_xor(ps[r], m2, 64);
        }
        if (lr == 0) {
            #pragma unroll
            for (int r = 0; r < 4; ++r) {
                int row = bm + wr * 32 + mi * 16 + lk * 4 + r;
                partial[(size_t)row * 32 + by * 2 + wc] = ps[r];
            }
        }
    }
}

// ---------------- ysum: y[r] = sum(partial[r][:]) + b4 ----------------
__global__ __launch_bounds__(256) void ysum_k(const float* __restrict__ partial,
                                              const float* __restrict__ b4,
                                              float* __restrict__ y) {
    int r = blockIdx.x * 256 + threadIdx.x;
    float s = 0.f;
    #pragma unroll
    for (int q = 0; q < 8; ++q) {
        float4 v = *(const float4*)&partial[(size_t)r * 32 + q * 4];
        s += v.x + v.y + v.z + v.w;
    }
    y[r] = s + b4[0];
}

extern "C" void kernel_launch(void* const* d_in, const int* in_sizes, int n_in,
                              void* d_out, int out_size, void* d_ws, size_t ws_size,
                              hipStream_t stream) {
    const float* X  = (const float*)d_in[0];
    const int*   p  = (const int*)d_in[1];
    const float* W1 = (const float*)d_in[2];
    const float* b1 = (const float*)d_in[3];
    const float* W2 = (const float*)d_in[4];
    const float* b2 = (const float*)d_in[5];
    const float* W3 = (const float*)d_in[6];
    const float* b3 = (const float*)d_in[7];
    const float* W4 = (const float*)d_in[8];
    const float* b4 = (const float*)d_in[9];
    float* out = (float*)d_out;

    char* ws = (char*)d_ws;
    size_t off = 0;
    float* psum = (float*)(ws + off); off += (size_t)NCH * PP * 4;
    unsigned short* h2h = (unsigned short*)(ws + off); off += (size_t)PP * HH * 2;
    unsigned short* h2l = (unsigned short*)(ws + off); off += (size_t)PP * HH * 2;
    unsigned short* w2h = (unsigned short*)(ws + off); off += (size_t)HH * HH * 2;
    unsigned short* w2l = (unsigned short*)(ws + off); off += (size_t)HH * HH * 2;
    unsigned short* w3h = (unsigned short*)(ws + off); off += (size_t)HH * HH * 2;
    unsigned short* w3l = (unsigned short*)(ws + off); off += (size_t)HH * HH * 2;
    float* partial = (float*)(ws + off); off += (size_t)PP * 32 * 4;

    pre_k<<<1024, 256, 0, stream>>>(X, p, psum, W2, w2h, w2l, W3, w3h, w3l);
    gemm1_k<<<256, 512, 0, stream>>>(psum, W1, b1, w2h, w2l, b2, h2h, h2l);
    gemm2_k<<<256, 512, 0, stream>>>(h2h, h2l, w3h, w3l, b3, W4, partial);
    ysum_k<<<PP / 256, 256, 0, stream>>>(partial, b4, out);
}